// Round 1
// baseline (408.894 us; speedup 1.0000x reference)
//
#include <hip/hip_runtime.h>
#include <hip/hip_bf16.h>
#include <math.h>

#define NT   16384
#define DM   1024
#define NSEG 4
#define HS   1024
#define CAP  16384
#define BK   64

typedef __attribute__((ext_vector_type(8))) short bf16x8;
typedef __attribute__((ext_vector_type(4))) float f32x4;

typedef __attribute__((address_space(1))) unsigned int gu32;
typedef __attribute__((address_space(3))) unsigned int lu32;

// Direct global->LDS DMA, 16 B per lane. LDS dest must be wave-uniform;
// HW writes lane i at base + 16*i. Global address may differ per lane.
__device__ __forceinline__ void gll16(const void* g, void* l) {
  __builtin_amdgcn_global_load_lds((gu32*)(unsigned long long)g,
                                   (lu32*)(unsigned int)(unsigned long long)l,
                                   16, 0, 0);
}

__device__ __forceinline__ unsigned short cvt_bf16(float f) {
  unsigned int u = __float_as_uint(f);
  u += 0x7fffu + ((u >> 16) & 1u);   // round-to-nearest-even
  return (unsigned short)(u >> 16);
}

// ---------------- tiny setup kernels ----------------

__global__ void k_init(int* meta) {
  int t = threadIdx.x;
  if (t < NSEG) meta[t] = 0;
  if (t == NSEG) meta[NSEG] = 1;   // assume int64 until proven otherwise
}

// If indices are genuinely int32, some odd 32-bit word is nonzero (values 0..3,
// 16384 samples). If they are int64 (LE), every odd word is 0.
__global__ void k_detect(const int* __restrict__ idx32, int* meta) {
  int t = blockIdx.x * 256 + threadIdx.x;   // 8192 threads
  if (t < NT / 2 && idx32[2 * t + 1] != 0) meta[NSEG] = 0;
}

__global__ void k_perm(const int* __restrict__ idx, int* meta, int* __restrict__ perm) {
  int t = blockIdx.x * 256 + threadIdx.x;
  if (t < NT) {
    int is64 = meta[NSEG];
    int s = is64 ? idx[2 * t] : idx[t];
    int p = atomicAdd(&meta[s], 1);
    perm[s * CAP + p] = t;
  }
}

// x f32 -> bf16, same layout. 8 elems/thread.
__global__ void k_cvt_x(const float4* __restrict__ x, uint4* __restrict__ xb) {
  int i = blockIdx.x * 256 + threadIdx.x;
  float4 a = x[2 * i];
  float4 b = x[2 * i + 1];
  uint4 o;
  o.x = cvt_bf16(a.x) | ((unsigned)cvt_bf16(a.y) << 16);
  o.y = cvt_bf16(a.z) | ((unsigned)cvt_bf16(a.w) << 16);
  o.z = cvt_bf16(b.x) | ((unsigned)cvt_bf16(b.y) << 16);
  o.w = cvt_bf16(b.z) | ((unsigned)cvt_bf16(b.w) << 16);
  xb[i] = o;
}

// Transpose 1024x1024 f32 -> bf16 [out][in], per (matrix, seg). z = mtx*4+seg.
__global__ void k_trans_w(const float* __restrict__ gw, const float* __restrict__ uw,
                          const float* __restrict__ dw,
                          unsigned short* __restrict__ gwt, unsigned short* __restrict__ uwt,
                          unsigned short* __restrict__ dwt) {
  __shared__ float tile[32][33];
  int z = blockIdx.z, mtx = z >> 2, s = z & 3;
  const float* src = (mtx == 0 ? gw : mtx == 1 ? uw : dw) + (size_t)s * DM * HS;
  unsigned short* dst = (mtx == 0 ? gwt : mtx == 1 ? uwt : dwt) + (size_t)s * DM * HS;
  int c0 = blockIdx.x * 32, r0 = blockIdx.y * 32;
  for (int i = threadIdx.y; i < 32; i += 8)
    tile[i][threadIdx.x] = src[(size_t)(r0 + i) * 1024 + c0 + threadIdx.x];
  __syncthreads();
  for (int i = threadIdx.y; i < 32; i += 8)
    dst[(size_t)(c0 + i) * 1024 + r0 + threadIdx.x] = cvt_bf16(tile[threadIdx.x][i]);
}

// ---------------- GEMM 1: gate+up fused, silu epilogue ----------------
// A: xb rows gathered via perm [m][k]; B: gwt/uwt [n][k] (pre-transposed).
// BM=128, BN=64 (x2 matrices), BK=64. 4 waves, each 64x32 per matrix.
// XOR swizzle applied on the global-source side so frag ds_read_b128 are
// conflict-free despite global_load_lds's forced contiguous LDS layout.

__global__ __launch_bounds__(256) void k_gateup(
    const unsigned short* __restrict__ xb,
    const unsigned short* __restrict__ gwt,
    const unsigned short* __restrict__ uwt,
    const int* __restrict__ meta,
    const int* __restrict__ perm,
    unsigned short* __restrict__ hidden) {
  const int seg = blockIdx.z;
  const int count = meta[seg];
  const int m0 = blockIdx.y * 128;
  if (m0 >= count) return;
  const int n0 = blockIdx.x * 64;

  __shared__ __align__(16) unsigned short As[128 * BK];
  __shared__ __align__(16) unsigned short Bg[64 * BK];
  __shared__ __align__(16) unsigned short Bu[64 * BK];

  const int tid = threadIdx.x;
  const int lane = tid & 63;
  const int wave = tid >> 6;
  const int* pseg = perm + seg * CAP;

  int a_off[4];
#pragma unroll
  for (int is = 0; is < 4; ++is) {
    int c = is * 256 + tid;          // chunk 0..1023
    int m = c >> 3;
    int kb = (c & 7) ^ (m & 7);      // swizzled source k-chunk
    int row = m0 + m;
    row = row < count ? row : count - 1;
    a_off[is] = pseg[row] * DM + kb * 8;
  }
  int b_off[2];
#pragma unroll
  for (int is = 0; is < 2; ++is) {
    int c = is * 256 + tid;          // chunk 0..511
    int n = c >> 3;
    int kb = (c & 7) ^ (n & 7);
    b_off[is] = (seg * HS + n0 + n) * DM + kb * 8;
  }

  f32x4 accg[4][2] = {};
  f32x4 accu[4][2] = {};
  const int wm = (wave & 1) * 64;
  const int wn = (wave >> 1) * 32;
  const int fm = lane & 15;
  const int fq = lane >> 4;
  const int fx = lane & 7;

  for (int kt = 0; kt < DM / BK; ++kt) {
    const int k0 = kt * BK;
    __syncthreads();
#pragma unroll
    for (int is = 0; is < 4; ++is)
      gll16(xb + a_off[is] + k0, (char*)As + (is * 256 + wave * 64) * 16);
#pragma unroll
    for (int is = 0; is < 2; ++is) {
      gll16(gwt + b_off[is] + k0, (char*)Bg + (is * 256 + wave * 64) * 16);
      gll16(uwt + b_off[is] + k0, (char*)Bu + (is * 256 + wave * 64) * 16);
    }
    __syncthreads();
#pragma unroll
    for (int s = 0; s < 2; ++s) {
      bf16x8 af[4], bgf[2], buf_[2];
      const int kb = (s * 4 + fq) ^ fx;
#pragma unroll
      for (int mi = 0; mi < 4; ++mi)
        af[mi] = *(const bf16x8*)((const char*)As + (((wm + mi * 16 + fm) * 8) + kb) * 16);
#pragma unroll
      for (int ni = 0; ni < 2; ++ni) {
        bgf[ni] = *(const bf16x8*)((const char*)Bg + (((wn + ni * 16 + fm) * 8) + kb) * 16);
        buf_[ni] = *(const bf16x8*)((const char*)Bu + (((wn + ni * 16 + fm) * 8) + kb) * 16);
      }
#pragma unroll
      for (int mi = 0; mi < 4; ++mi)
#pragma unroll
        for (int ni = 0; ni < 2; ++ni) {
          accg[mi][ni] = __builtin_amdgcn_mfma_f32_16x16x32_bf16(af[mi], bgf[ni], accg[mi][ni], 0, 0, 0);
          accu[mi][ni] = __builtin_amdgcn_mfma_f32_16x16x32_bf16(af[mi], buf_[ni], accu[mi][ni], 0, 0, 0);
        }
    }
  }

  const int rq = fq * 4;
#pragma unroll
  for (int mi = 0; mi < 4; ++mi) {
#pragma unroll
    for (int r = 0; r < 4; ++r) {
      int row = m0 + wm + mi * 16 + rq + r;
      if (row < count) {
        int t = pseg[row];
        unsigned short* h = hidden + t * HS + n0 + wn;
#pragma unroll
        for (int ni = 0; ni < 2; ++ni) {
          float g = accg[mi][ni][r];
          float u = accu[mi][ni][r];
          float sig = 1.0f / (1.0f + __expf(-g));
          h[ni * 16 + fm] = cvt_bf16(g * sig * u);
        }
      }
    }
  }
}

// ---------------- GEMM 2: down, scatter to out ----------------
// BM=128, BN=128, BK=64, 4 waves each 64x64.

__global__ __launch_bounds__(256) void k_down(
    const unsigned short* __restrict__ hidden,
    const unsigned short* __restrict__ dwt,
    const int* __restrict__ meta,
    const int* __restrict__ perm,
    float* __restrict__ out) {
  const int seg = blockIdx.z;
  const int count = meta[seg];
  const int m0 = blockIdx.y * 128;
  if (m0 >= count) return;
  const int n0 = blockIdx.x * 128;

  __shared__ __align__(16) unsigned short As[128 * BK];
  __shared__ __align__(16) unsigned short Bs[128 * BK];

  const int tid = threadIdx.x;
  const int lane = tid & 63;
  const int wave = tid >> 6;
  const int* pseg = perm + seg * CAP;

  int a_off[4], b_off[4];
#pragma unroll
  for (int is = 0; is < 4; ++is) {
    int c = is * 256 + tid;
    int m = c >> 3;
    int kb = (c & 7) ^ (m & 7);
    int row = m0 + m;
    row = row < count ? row : count - 1;
    a_off[is] = pseg[row] * HS + kb * 8;
    b_off[is] = (seg * DM + n0 + m) * HS + kb * 8;
  }

  f32x4 acc[4][4] = {};
  const int wm = (wave & 1) * 64;
  const int wn = (wave >> 1) * 64;
  const int fm = lane & 15;
  const int fq = lane >> 4;
  const int fx = lane & 7;

  for (int kt = 0; kt < HS / BK; ++kt) {
    const int k0 = kt * BK;
    __syncthreads();
#pragma unroll
    for (int is = 0; is < 4; ++is) {
      gll16(hidden + a_off[is] + k0, (char*)As + (is * 256 + wave * 64) * 16);
      gll16(dwt + b_off[is] + k0, (char*)Bs + (is * 256 + wave * 64) * 16);
    }
    __syncthreads();
#pragma unroll
    for (int s = 0; s < 2; ++s) {
      bf16x8 af[4], bf[4];
      const int kb = (s * 4 + fq) ^ fx;
#pragma unroll
      for (int mi = 0; mi < 4; ++mi)
        af[mi] = *(const bf16x8*)((const char*)As + (((wm + mi * 16 + fm) * 8) + kb) * 16);
#pragma unroll
      for (int ni = 0; ni < 4; ++ni)
        bf[ni] = *(const bf16x8*)((const char*)Bs + (((wn + ni * 16 + fm) * 8) + kb) * 16);
#pragma unroll
      for (int mi = 0; mi < 4; ++mi)
#pragma unroll
        for (int ni = 0; ni < 4; ++ni)
          acc[mi][ni] = __builtin_amdgcn_mfma_f32_16x16x32_bf16(af[mi], bf[ni], acc[mi][ni], 0, 0, 0);
    }
  }

  const int rq = fq * 4;
#pragma unroll
  for (int mi = 0; mi < 4; ++mi) {
#pragma unroll
    for (int r = 0; r < 4; ++r) {
      int row = m0 + wm + mi * 16 + rq + r;
      if (row < count) {
        float* o = out + pseg[row] * DM + n0 + wn;
#pragma unroll
        for (int ni = 0; ni < 4; ++ni)
          o[ni * 16 + fm] = acc[mi][ni][r];
      }
    }
  }
}

// ---------------- launch ----------------

extern "C" void kernel_launch(void* const* d_in, const int* in_sizes, int n_in,
                              void* d_out, int out_size, void* d_ws, size_t ws_size,
                              hipStream_t stream) {
  const float* x  = (const float*)d_in[0];
  const float* gw = (const float*)d_in[1];
  const float* uw = (const float*)d_in[2];
  const float* dw = (const float*)d_in[3];
  const int* tsi  = (const int*)d_in[4];
  float* out = (float*)d_out;

  char* ws = (char*)d_ws;
  int* meta = (int*)ws;                                  // [0..3]=counts, [4]=is64 flag
  int* perm = (int*)(ws + 1024);                         // 65536 ints (256 KiB)
  unsigned short* xb  = (unsigned short*)(ws + (1 << 19));  // 512 KiB offset, 32 MiB
  unsigned short* gwt = xb + (size_t)NT * DM;               // 8 MiB
  unsigned short* uwt = gwt + (size_t)NSEG * HS * DM;       // 8 MiB
  unsigned short* dwt = uwt + (size_t)NSEG * HS * DM;       // 8 MiB
  unsigned short* hid = dwt + (size_t)NSEG * DM * HS;       // 32 MiB

  k_init<<<1, 64, 0, stream>>>(meta);
  k_detect<<<NT / 512, 256, 0, stream>>>(tsi, meta);
  k_cvt_x<<<NT * DM / 8 / 256, 256, 0, stream>>>((const float4*)x, (uint4*)xb);
  k_trans_w<<<dim3(32, 32, 12), dim3(32, 8), 0, stream>>>(gw, uw, dw, gwt, uwt, dwt);
  k_perm<<<NT / 256, 256, 0, stream>>>(tsi, meta, perm);
  k_gateup<<<dim3(16, 128, 4), 256, 0, stream>>>(xb, gwt, uwt, meta, perm, hid);
  k_down<<<dim3(8, 128, 4), 256, 0, stream>>>(hid, dwt, meta, perm, out);
}

// Round 2
// 337.627 us; speedup vs baseline: 1.2111x; 1.2111x over previous
//
#include <hip/hip_runtime.h>
#include <hip/hip_bf16.h>
#include <math.h>

#define NT   16384
#define DM   1024
#define NSEG 4
#define BK   64
#define HS   1024

typedef __attribute__((ext_vector_type(8))) short bf16x8;
typedef __attribute__((ext_vector_type(4))) float f32x4;

typedef __attribute__((address_space(1))) unsigned int gu32;
typedef __attribute__((address_space(3))) unsigned int lu32;

__device__ __forceinline__ void gll16(const void* g, void* l) {
  __builtin_amdgcn_global_load_lds((gu32*)(unsigned long long)g,
                                   (lu32*)(unsigned int)(unsigned long long)l,
                                   16, 0, 0);
}

__device__ __forceinline__ unsigned short cvt_bf16(float f) {
  unsigned int u = __float_as_uint(f);
  u += 0x7fffu + ((u >> 16) & 1u);   // RNE
  return (unsigned short)(u >> 16);
}

// meta layout: [0..3]=counts  [4]=is32 flag  [5..8]=seg base  [9..12]=cursors

__global__ void k_init(int* meta) {
  if (threadIdx.x < 16) meta[threadIdx.x] = 0;
}

// int64 (LE) indices have all odd 32-bit words zero; int32 indices don't.
__global__ void k_detect(const int* __restrict__ idx32, int* meta) {
  int t = blockIdx.x * 256 + threadIdx.x;       // 8192 threads cover NT/2 pairs
  int lane = threadIdx.x & 63;
  unsigned long long m = __ballot(idx32[2 * t + 1] != 0);
  if (lane == 0 && m) atomicOr(&meta[4], 1);
}

__global__ void k_count(const int* __restrict__ idx, int* meta) {
  int t = blockIdx.x * 256 + threadIdx.x;
  int s = meta[4] ? idx[t] : idx[2 * t];
  int lane = threadIdx.x & 63;
#pragma unroll
  for (int q = 0; q < 4; ++q) {
    unsigned long long m = __ballot(s == q);
    if (lane == 0 && m) atomicAdd(&meta[q], (int)__popcll(m));
  }
}

__global__ void k_base(int* meta) {
  int c0 = meta[0], c1 = meta[1], c2 = meta[2];
  meta[5] = 0; meta[6] = c0; meta[7] = c0 + c1; meta[8] = c0 + c1 + c2;
  meta[9] = 0; meta[10] = c0; meta[11] = c0 + c1; meta[12] = c0 + c1 + c2;
}

__global__ void k_rank(const int* __restrict__ idx, int* meta,
                       int* __restrict__ rank, int* __restrict__ perm) {
  int t = blockIdx.x * 256 + threadIdx.x;
  int s = meta[4] ? idx[t] : idx[2 * t];
  int lane = threadIdx.x & 63;
  unsigned long long lt = (1ull << lane) - 1;
#pragma unroll
  for (int q = 0; q < 4; ++q) {
    unsigned long long m = __ballot(s == q);
    int wb = 0;
    if (lane == 0 && m) wb = atomicAdd(&meta[9 + q], (int)__popcll(m));
    wb = __shfl(wb, 0);
    if (s == q) {
      int r = wb + (int)__popcll(m & lt);
      rank[t] = r;
      perm[r] = t;
    }
  }
}

// x f32 [t][1024] -> bf16 compacted [rank[t]][1024]. 2 tokens per block.
__global__ __launch_bounds__(256) void k_cvt_x(const float4* __restrict__ x,
                                               const int* __restrict__ rank,
                                               uint4* __restrict__ xc) {
  int tid = threadIdx.x;
  int tok = blockIdx.x * 2 + (tid >> 7);
  int li = tid & 127;                 // 8 f32 per lane
  int r = rank[tok];
  float4 a = x[tok * 256 + li * 2];
  float4 b = x[tok * 256 + li * 2 + 1];
  uint4 o;
  o.x = cvt_bf16(a.x) | ((unsigned)cvt_bf16(a.y) << 16);
  o.y = cvt_bf16(a.z) | ((unsigned)cvt_bf16(a.w) << 16);
  o.z = cvt_bf16(b.x) | ((unsigned)cvt_bf16(b.y) << 16);
  o.w = cvt_bf16(b.z) | ((unsigned)cvt_bf16(b.w) << 16);
  xc[r * 128 + li] = o;
}

// Transpose 1024x1024 f32 [k][n] -> bf16 [n][k], per (matrix, seg). z = mtx*4+seg.
__global__ __launch_bounds__(256) void k_trans_w(
    const float* __restrict__ gw, const float* __restrict__ uw, const float* __restrict__ dw,
    unsigned short* __restrict__ gwt, unsigned short* __restrict__ uwt,
    unsigned short* __restrict__ dwt) {
  __shared__ float tile[64][65];
  int z = blockIdx.z, mtx = z >> 2, s = z & 3;
  const float* src = (mtx == 0 ? gw : mtx == 1 ? uw : dw) + (size_t)s * DM * HS;
  unsigned short* dst = (mtx == 0 ? gwt : mtx == 1 ? uwt : dwt) + (size_t)s * DM * HS;
  int k0 = blockIdx.y * 64, n0 = blockIdx.x * 64;
  int col = threadIdx.x & 63, rb = threadIdx.x >> 6;
#pragma unroll
  for (int i = 0; i < 64; i += 4)
    tile[i + rb][col] = src[(size_t)(k0 + i + rb) * 1024 + n0 + col];
  __syncthreads();
  int kp = threadIdx.x & 31, nb = threadIdx.x >> 5;
#pragma unroll
  for (int j = 0; j < 64; j += 8) {
    int nn = j + nb;
    unsigned int w = (unsigned)cvt_bf16(tile[2 * kp][nn]) |
                     ((unsigned)cvt_bf16(tile[2 * kp + 1][nn]) << 16);
    *(unsigned int*)(dst + (size_t)(n0 + nn) * 1024 + k0 + 2 * kp) = w;
  }
}

// ---------------- GEMM 1: gate+up fused, silu epilogue, compacted rows ----
__global__ __launch_bounds__(256) void k_gateup(
    const unsigned short* __restrict__ xc,
    const unsigned short* __restrict__ gwt,
    const unsigned short* __restrict__ uwt,
    const int* __restrict__ meta,
    unsigned short* __restrict__ hidden) {
  const int seg = blockIdx.z;
  const int count = meta[seg];
  const int m0 = blockIdx.y * 128;
  if (m0 >= count) return;
  const int base = meta[5 + seg];
  const int n0 = blockIdx.x * 64;

  __shared__ __align__(16) unsigned short As[128 * BK];
  __shared__ __align__(16) unsigned short Bg[64 * BK];
  __shared__ __align__(16) unsigned short Bu[64 * BK];

  const int tid = threadIdx.x;
  const int lane = tid & 63;
  const int wave = tid >> 6;

  int a_off[4];
#pragma unroll
  for (int is = 0; is < 4; ++is) {
    int c = is * 256 + tid;
    int m = c >> 3;
    int kb = (c & 7) ^ (m & 7);
    int row = m0 + m;
    row = row < count ? row : count - 1;
    a_off[is] = (base + row) * DM + kb * 8;
  }
  int b_off[2];
#pragma unroll
  for (int is = 0; is < 2; ++is) {
    int c = is * 256 + tid;
    int n = c >> 3;
    int kb = (c & 7) ^ (n & 7);
    b_off[is] = (seg * HS + n0 + n) * DM + kb * 8;
  }

  f32x4 accg[4][2] = {};
  f32x4 accu[4][2] = {};
  const int wm = (wave & 1) * 64;
  const int wn = (wave >> 1) * 32;
  const int fm = lane & 15;
  const int fq = lane >> 4;
  const int fx = lane & 7;

  for (int kt = 0; kt < DM / BK; ++kt) {
    const int k0 = kt * BK;
    __syncthreads();
#pragma unroll
    for (int is = 0; is < 4; ++is)
      gll16(xc + a_off[is] + k0, (char*)As + (is * 256 + wave * 64) * 16);
#pragma unroll
    for (int is = 0; is < 2; ++is) {
      gll16(gwt + b_off[is] + k0, (char*)Bg + (is * 256 + wave * 64) * 16);
      gll16(uwt + b_off[is] + k0, (char*)Bu + (is * 256 + wave * 64) * 16);
    }
    __syncthreads();
#pragma unroll
    for (int s = 0; s < 2; ++s) {
      bf16x8 af[4], bgf[2], buf_[2];
      const int kb = (s * 4 + fq) ^ fx;
#pragma unroll
      for (int mi = 0; mi < 4; ++mi)
        af[mi] = *(const bf16x8*)((const char*)As + (((wm + mi * 16 + fm) * 8) + kb) * 16);
#pragma unroll
      for (int ni = 0; ni < 2; ++ni) {
        bgf[ni] = *(const bf16x8*)((const char*)Bg + (((wn + ni * 16 + fm) * 8) + kb) * 16);
        buf_[ni] = *(const bf16x8*)((const char*)Bu + (((wn + ni * 16 + fm) * 8) + kb) * 16);
      }
#pragma unroll
      for (int mi = 0; mi < 4; ++mi)
#pragma unroll
        for (int ni = 0; ni < 2; ++ni) {
          accg[mi][ni] = __builtin_amdgcn_mfma_f32_16x16x32_bf16(af[mi], bgf[ni], accg[mi][ni], 0, 0, 0);
          accu[mi][ni] = __builtin_amdgcn_mfma_f32_16x16x32_bf16(af[mi], buf_[ni], accu[mi][ni], 0, 0, 0);
        }
    }
  }

  const int rq = fq * 4;
#pragma unroll
  for (int mi = 0; mi < 4; ++mi) {
#pragma unroll
    for (int r = 0; r < 4; ++r) {
      int row = m0 + wm + mi * 16 + rq + r;
      if (row < count) {
        unsigned short* h = hidden + (size_t)(base + row) * HS + n0 + wn;
#pragma unroll
        for (int ni = 0; ni < 2; ++ni) {
          float g = accg[mi][ni][r];
          float u = accu[mi][ni][r];
          float sig = 1.0f / (1.0f + __expf(-g));
          h[ni * 16 + fm] = cvt_bf16(g * sig * u);
        }
      }
    }
  }
}

// ---------------- GEMM 2: down, scatter rows to out ----------------
__global__ __launch_bounds__(256) void k_down(
    const unsigned short* __restrict__ hidden,
    const unsigned short* __restrict__ dwt,
    const int* __restrict__ meta,
    const int* __restrict__ perm,
    float* __restrict__ out) {
  const int seg = blockIdx.z;
  const int count = meta[seg];
  const int m0 = blockIdx.y * 128;
  if (m0 >= count) return;
  const int base = meta[5 + seg];
  const int n0 = blockIdx.x * 128;

  __shared__ __align__(16) unsigned short As[128 * BK];
  __shared__ __align__(16) unsigned short Bs[128 * BK];

  const int tid = threadIdx.x;
  const int lane = tid & 63;
  const int wave = tid >> 6;

  int a_off[4], b_off[4];
#pragma unroll
  for (int is = 0; is < 4; ++is) {
    int c = is * 256 + tid;
    int m = c >> 3;
    int kb = (c & 7) ^ (m & 7);
    int row = m0 + m;
    row = row < count ? row : count - 1;
    a_off[is] = (base + row) * HS + kb * 8;
    b_off[is] = (seg * DM + n0 + m) * HS + kb * 8;
  }

  f32x4 acc[4][4] = {};
  const int wm = (wave & 1) * 64;
  const int wn = (wave >> 1) * 64;
  const int fm = lane & 15;
  const int fq = lane >> 4;
  const int fx = lane & 7;

  for (int kt = 0; kt < HS / BK; ++kt) {
    const int k0 = kt * BK;
    __syncthreads();
#pragma unroll
    for (int is = 0; is < 4; ++is) {
      gll16(hidden + a_off[is] + k0, (char*)As + (is * 256 + wave * 64) * 16);
      gll16(dwt + b_off[is] + k0, (char*)Bs + (is * 256 + wave * 64) * 16);
    }
    __syncthreads();
#pragma unroll
    for (int s = 0; s < 2; ++s) {
      bf16x8 af[4], bf[4];
      const int kb = (s * 4 + fq) ^ fx;
#pragma unroll
      for (int mi = 0; mi < 4; ++mi)
        af[mi] = *(const bf16x8*)((const char*)As + (((wm + mi * 16 + fm) * 8) + kb) * 16);
#pragma unroll
      for (int ni = 0; ni < 4; ++ni)
        bf[ni] = *(const bf16x8*)((const char*)Bs + (((wn + ni * 16 + fm) * 8) + kb) * 16);
#pragma unroll
      for (int mi = 0; mi < 4; ++mi)
#pragma unroll
        for (int ni = 0; ni < 4; ++ni)
          acc[mi][ni] = __builtin_amdgcn_mfma_f32_16x16x32_bf16(af[mi], bf[ni], acc[mi][ni], 0, 0, 0);
    }
  }

  const int rq = fq * 4;
#pragma unroll
  for (int mi = 0; mi < 4; ++mi) {
#pragma unroll
    for (int r = 0; r < 4; ++r) {
      int row = m0 + wm + mi * 16 + rq + r;
      if (row < count) {
        int t = perm[base + row];
        float* o = out + (size_t)t * DM + n0 + wn;
#pragma unroll
        for (int ni = 0; ni < 4; ++ni)
          o[ni * 16 + fm] = acc[mi][ni][r];
      }
    }
  }
}

// ---------------- launch ----------------

extern "C" void kernel_launch(void* const* d_in, const int* in_sizes, int n_in,
                              void* d_out, int out_size, void* d_ws, size_t ws_size,
                              hipStream_t stream) {
  const float* x  = (const float*)d_in[0];
  const float* gw = (const float*)d_in[1];
  const float* uw = (const float*)d_in[2];
  const float* dw = (const float*)d_in[3];
  const int* tsi  = (const int*)d_in[4];
  float* out = (float*)d_out;

  char* ws = (char*)d_ws;
  int* meta = (int*)ws;
  int* rank = (int*)(ws + 1024);                            // NT ints
  int* perm = (int*)(ws + 1024 + NT * 4);                   // NT ints
  unsigned short* xc  = (unsigned short*)(ws + (1 << 19));  // 32 MiB, compacted
  unsigned short* gwt = xc + (size_t)NT * DM;               // 8 MiB
  unsigned short* uwt = gwt + (size_t)NSEG * HS * DM;       // 8 MiB
  unsigned short* dwt = uwt + (size_t)NSEG * HS * DM;       // 8 MiB
  unsigned short* hid = dwt + (size_t)NSEG * DM * HS;       // 32 MiB, compacted

  k_init<<<1, 64, 0, stream>>>(meta);
  k_detect<<<NT / 512, 256, 0, stream>>>(tsi, meta);
  k_count<<<NT / 256, 256, 0, stream>>>(tsi, meta);
  k_base<<<1, 1, 0, stream>>>(meta);
  k_rank<<<NT / 256, 256, 0, stream>>>(tsi, meta, rank, perm);
  k_cvt_x<<<NT / 2, 256, 0, stream>>>((const float4*)x, rank, (uint4*)xc);
  k_trans_w<<<dim3(16, 16, 12), 256, 0, stream>>>(gw, uw, dw, gwt, uwt, dwt);
  k_gateup<<<dim3(16, 128, 4), 256, 0, stream>>>(xc, gwt, uwt, meta, hid);
  k_down<<<dim3(8, 128, 4), 256, 0, stream>>>(hid, dwt, meta, perm, out);
}

// Round 3
// 334.225 us; speedup vs baseline: 1.2234x; 1.0102x over previous
//
#include <hip/hip_runtime.h>
#include <hip/hip_bf16.h>
#include <math.h>

#define NT   16384
#define DM   1024
#define NSEG 4
#define BK   64
#define HS   1024

typedef __attribute__((ext_vector_type(8))) short bf16x8;
typedef __attribute__((ext_vector_type(4))) float f32x4;

typedef __attribute__((address_space(1))) unsigned int gu32;
typedef __attribute__((address_space(3))) unsigned int lu32;

__device__ __forceinline__ void gll16(const void* g, void* l) {
  __builtin_amdgcn_global_load_lds((gu32*)(unsigned long long)g,
                                   (lu32*)(unsigned int)(unsigned long long)l,
                                   16, 0, 0);
}

__device__ __forceinline__ unsigned short cvt_bf16(float f) {
  unsigned int u = __float_as_uint(f);
  u += 0x7fffu + ((u >> 16) & 1u);   // RNE
  return (unsigned short)(u >> 16);
}

// meta: [0..3]=counts [4]=is32 [5..8]=seg base [9..12]=cursors

// Dual-interpretation count: per-block partials, no global init needed.
// part[b][0..3]=counts of even-word seg hits, [4..7]=odd-word hits, [8]=any odd word nonzero.
__global__ __launch_bounds__(256) void k_scan(const int* __restrict__ idx, int* __restrict__ part) {
  __shared__ int c[9];
  int tid = threadIdx.x;
  if (tid < 9) c[tid] = 0;
  __syncthreads();
  int t = blockIdx.x * 256 + tid;          // 8192 threads cover 8192 word-pairs
  int w0 = idx[2 * t], w1 = idx[2 * t + 1];
  int lane = tid & 63;
  unsigned long long m;
#pragma unroll
  for (int q = 0; q < 4; ++q) {
    m = __ballot(w0 == q); if (lane == 0 && m) atomicAdd(&c[q], (int)__popcll(m));
    m = __ballot(w1 == q); if (lane == 0 && m) atomicAdd(&c[4 + q], (int)__popcll(m));
  }
  m = __ballot(w1 != 0);
  if (lane == 0 && m) atomicAdd(&c[8], 1);
  __syncthreads();
  if (tid < 9) part[blockIdx.x * 9 + tid] = c[tid];
}

__global__ void k_base(const int* __restrict__ part, int* __restrict__ meta, int2* __restrict__ table) {
  __shared__ int c[9];
  int t = threadIdx.x;
  if (t < 9) {
    int s = 0;
    for (int b = 0; b < 32; ++b) s += part[b * 9 + t];
    c[t] = s;
  }
  __syncthreads();
  if (t == 0) {
    int flag = (c[8] != 0);                 // 1 => int32 indices
    meta[4] = flag;
    int base = 0;
    for (int s = 0; s < 4; ++s) {
      int cnt = flag ? (c[s] + c[4 + s]) : c[s];
      meta[s] = cnt; meta[5 + s] = base; meta[9 + s] = base;
      base += cnt;
    }
    int nt = 0;
    for (int s = 0; s < 4; ++s)
      for (int m0 = 0; m0 < meta[s]; m0 += 128) table[nt++] = make_int2(s, m0);
    for (; nt < 132; ++nt) table[nt] = make_int2(-1, 0);
  }
}

__global__ void k_rank(const int* __restrict__ idx, int* __restrict__ meta,
                       int* __restrict__ rank, int* __restrict__ perm) {
  int t = blockIdx.x * 256 + threadIdx.x;
  int s = meta[4] ? idx[t] : idx[2 * t];
  int lane = threadIdx.x & 63;
  unsigned long long lt = (1ull << lane) - 1;
#pragma unroll
  for (int q = 0; q < 4; ++q) {
    unsigned long long m = __ballot(s == q);
    int wb = 0;
    if (lane == 0 && m) wb = atomicAdd(&meta[9 + q], (int)__popcll(m));
    wb = __shfl(wb, 0);
    if (s == q) {
      int r = wb + (int)__popcll(m & lt);
      rank[t] = r;
      perm[r] = t;
    }
  }
}

// k_prep: blocks [0,8192): x f32 -> bf16 compacted by rank (2 tokens/block).
//         blocks [8192,10240): transpose gate/up weights f32[k][n] -> bf16[n][k].
__global__ __launch_bounds__(256) void k_prep(
    const float4* __restrict__ x, const int* __restrict__ rank, uint4* __restrict__ xc,
    const float* __restrict__ gw, const float* __restrict__ uw,
    unsigned short* __restrict__ gwt, unsigned short* __restrict__ uwt) {
  __shared__ float tile[64][65];
  int bid = blockIdx.x, tid = threadIdx.x;
  if (bid < 8192) {
    int tok = bid * 2 + (tid >> 7);
    int li = tid & 127;
    int r = rank[tok];
    float4 a = x[tok * 256 + li * 2];
    float4 b = x[tok * 256 + li * 2 + 1];
    uint4 o;
    o.x = cvt_bf16(a.x) | ((unsigned)cvt_bf16(a.y) << 16);
    o.y = cvt_bf16(a.z) | ((unsigned)cvt_bf16(a.w) << 16);
    o.z = cvt_bf16(b.x) | ((unsigned)cvt_bf16(b.y) << 16);
    o.w = cvt_bf16(b.z) | ((unsigned)cvt_bf16(b.w) << 16);
    xc[r * 128 + li] = o;
    return;
  }
  int tb = bid - 8192;                      // 0..2047
  int mtx = tb >> 10, seg = (tb >> 8) & 3, tl = tb & 255;
  const float* src = (mtx == 0 ? gw : uw) + (size_t)seg * DM * HS;
  unsigned short* dst = (mtx == 0 ? gwt : uwt) + (size_t)seg * DM * HS;
  int n0 = (tl & 15) * 64, k0 = (tl >> 4) * 64;
  int col = tid & 63, rb = tid >> 6;
#pragma unroll
  for (int i = 0; i < 64; i += 4)
    tile[i + rb][col] = src[(size_t)(k0 + i + rb) * 1024 + n0 + col];
  __syncthreads();
  int kp = tid & 31, nb = tid >> 5;
#pragma unroll
  for (int j = 0; j < 64; j += 8) {
    int nn = j + nb;
    unsigned int w = (unsigned)cvt_bf16(tile[2 * kp][nn]) |
                     ((unsigned)cvt_bf16(tile[2 * kp + 1][nn]) << 16);
    *(unsigned int*)(dst + (size_t)(n0 + nn) * 1024 + k0 + 2 * kp) = w;
  }
}

// ---------------- GEMM 1: gate+up fused + dwt-transpose riders ----------------
__global__ __launch_bounds__(256) void k_gateup(
    const unsigned short* __restrict__ xc,
    const unsigned short* __restrict__ gwt,
    const unsigned short* __restrict__ uwt,
    const int* __restrict__ meta,
    const int2* __restrict__ table,
    const float* __restrict__ dw,
    unsigned short* __restrict__ dwt,
    unsigned short* __restrict__ hidden) {
  union Sm {
    struct { unsigned short As[128 * BK], Bg[64 * BK], Bu[64 * BK]; } g;
    float tile[64][65];
  };
  __shared__ Sm sm;
  const int bid = blockIdx.x, tid = threadIdx.x;

  if (bid < 1024) {   // down-weight transpose rider
    int seg = bid >> 8, tl = bid & 255;
    int n0t = (tl & 15) * 64, k0t = (tl >> 4) * 64;
    const float* src = dw + (size_t)seg * DM * HS;
    unsigned short* dst = dwt + (size_t)seg * DM * HS;
    int col = tid & 63, rb = tid >> 6;
#pragma unroll
    for (int i = 0; i < 64; i += 4)
      sm.tile[i + rb][col] = src[(size_t)(k0t + i + rb) * 1024 + n0t + col];
    __syncthreads();
    int kp = tid & 31, nb = tid >> 5;
#pragma unroll
    for (int j = 0; j < 64; j += 8) {
      int nn = j + nb;
      unsigned int w = (unsigned)cvt_bf16(sm.tile[2 * kp][nn]) |
                       ((unsigned)cvt_bf16(sm.tile[2 * kp + 1][nn]) << 16);
      *(unsigned int*)(dst + (size_t)(n0t + nn) * 1024 + k0t + 2 * kp) = w;
    }
    return;
  }

  const int g = bid - 1024;
  const int2 te = table[g >> 4];
  if (te.x < 0) return;
  const int seg = te.x, m0 = te.y;
  const int count = meta[seg], base = meta[5 + seg];
  const int n0 = (g & 15) * 64;

  const int lane = tid & 63;
  const int wave = tid >> 6;

  const unsigned short* ap[4];
#pragma unroll
  for (int is = 0; is < 4; ++is) {
    int c = is * 256 + tid;
    int m = c >> 3;
    int kb = (c & 7) ^ (m & 7);
    int row = m0 + m;
    row = row < count ? row : count - 1;
    ap[is] = xc + (size_t)(base + row) * DM + kb * 8;
  }
  const unsigned short *gp[2], *up[2];
#pragma unroll
  for (int is = 0; is < 2; ++is) {
    int c = is * 256 + tid;
    int n = c >> 3;
    int kb = (c & 7) ^ (n & 7);
    gp[is] = gwt + (size_t)(seg * HS + n0 + n) * DM + kb * 8;
    up[is] = uwt + (size_t)(seg * HS + n0 + n) * DM + kb * 8;
  }

  f32x4 accg[4][2] = {};
  f32x4 accu[4][2] = {};
  const int wm = (wave & 1) * 64;
  const int wn = (wave >> 1) * 32;
  const int fm = lane & 15;
  const int fq = lane >> 4;
  const int fx = lane & 7;
  // element-offset bases for the two k-substeps (all frag reads get imm offsets)
  const int a_e0 = (wm + fm) * 64 + ((fq) ^ fx) * 8;
  const int a_e1 = (wm + fm) * 64 + ((4 + fq) ^ fx) * 8;
  const int b_e0 = (wn + fm) * 64 + ((fq) ^ fx) * 8;
  const int b_e1 = (wn + fm) * 64 + ((4 + fq) ^ fx) * 8;

  for (int kt = 0; kt < DM / BK; ++kt) {
    __syncthreads();
#pragma unroll
    for (int is = 0; is < 4; ++is)
      gll16(ap[is], (char*)sm.g.As + (is * 256 + wave * 64) * 16);
#pragma unroll
    for (int is = 0; is < 2; ++is) {
      gll16(gp[is], (char*)sm.g.Bg + (is * 256 + wave * 64) * 16);
      gll16(up[is], (char*)sm.g.Bu + (is * 256 + wave * 64) * 16);
    }
#pragma unroll
    for (int is = 0; is < 4; ++is) ap[is] += BK;
#pragma unroll
    for (int is = 0; is < 2; ++is) { gp[is] += BK; up[is] += BK; }
    __syncthreads();
#pragma unroll
    for (int s = 0; s < 2; ++s) {
      const unsigned short* Ap = sm.g.As + (s ? a_e1 : a_e0);
      const unsigned short* Gp = sm.g.Bg + (s ? b_e1 : b_e0);
      const unsigned short* Up = sm.g.Bu + (s ? b_e1 : b_e0);
      bf16x8 af[4], bg2[2], bu2[2];
#pragma unroll
      for (int mi = 0; mi < 4; ++mi) af[mi] = *(const bf16x8*)(Ap + mi * 1024);
#pragma unroll
      for (int ni = 0; ni < 2; ++ni) {
        bg2[ni] = *(const bf16x8*)(Gp + ni * 1024);
        bu2[ni] = *(const bf16x8*)(Up + ni * 1024);
      }
#pragma unroll
      for (int mi = 0; mi < 4; ++mi)
#pragma unroll
        for (int ni = 0; ni < 2; ++ni) {
          accg[mi][ni] = __builtin_amdgcn_mfma_f32_16x16x32_bf16(af[mi], bg2[ni], accg[mi][ni], 0, 0, 0);
          accu[mi][ni] = __builtin_amdgcn_mfma_f32_16x16x32_bf16(af[mi], bu2[ni], accu[mi][ni], 0, 0, 0);
        }
    }
  }

  const int rq = fq * 4;
#pragma unroll
  for (int mi = 0; mi < 4; ++mi) {
#pragma unroll
    for (int r = 0; r < 4; ++r) {
      int row = m0 + wm + mi * 16 + rq + r;
      if (row < count) {
        unsigned short* h = hidden + (size_t)(base + row) * HS + n0 + wn;
#pragma unroll
        for (int ni = 0; ni < 2; ++ni) {
          float gv = accg[mi][ni][r];
          float uv = accu[mi][ni][r];
          float sig = 1.0f / (1.0f + __expf(-gv));
          h[ni * 16 + fm] = cvt_bf16(gv * sig * uv);
        }
      }
    }
  }
}

// ---------------- GEMM 2: down, scatter rows to out ----------------
__global__ __launch_bounds__(256) void k_down(
    const unsigned short* __restrict__ hidden,
    const unsigned short* __restrict__ dwt,
    const int* __restrict__ meta,
    const int2* __restrict__ table,
    const int* __restrict__ perm,
    float* __restrict__ out) {
  __shared__ __align__(16) unsigned short As[128 * BK];
  __shared__ __align__(16) unsigned short Bs[128 * BK];
  const int bid = blockIdx.x, tid = threadIdx.x;
  const int2 te = table[bid >> 3];
  if (te.x < 0) return;
  const int seg = te.x, m0 = te.y;
  const int count = meta[seg], base = meta[5 + seg];
  const int n0 = (bid & 7) * 128;

  const int lane = tid & 63;
  const int wave = tid >> 6;

  const unsigned short *ap[4], *bp[4];
#pragma unroll
  for (int is = 0; is < 4; ++is) {
    int c = is * 256 + tid;
    int m = c >> 3;
    int kb = (c & 7) ^ (m & 7);
    int row = m0 + m;
    row = row < count ? row : count - 1;
    ap[is] = hidden + (size_t)(base + row) * HS + kb * 8;
    bp[is] = dwt + (size_t)(seg * DM + n0 + m) * HS + kb * 8;
  }

  f32x4 acc[4][4] = {};
  const int wm = (wave & 1) * 64;
  const int wn = (wave >> 1) * 64;
  const int fm = lane & 15;
  const int fq = lane >> 4;
  const int fx = lane & 7;
  const int a_e0 = (wm + fm) * 64 + ((fq) ^ fx) * 8;
  const int a_e1 = (wm + fm) * 64 + ((4 + fq) ^ fx) * 8;
  const int b_e0 = (wn + fm) * 64 + ((fq) ^ fx) * 8;
  const int b_e1 = (wn + fm) * 64 + ((4 + fq) ^ fx) * 8;

  for (int kt = 0; kt < HS / BK; ++kt) {
    __syncthreads();
#pragma unroll
    for (int is = 0; is < 4; ++is) {
      gll16(ap[is], (char*)As + (is * 256 + wave * 64) * 16);
      gll16(bp[is], (char*)Bs + (is * 256 + wave * 64) * 16);
    }
#pragma unroll
    for (int is = 0; is < 4; ++is) { ap[is] += BK; bp[is] += BK; }
    __syncthreads();
#pragma unroll
    for (int s = 0; s < 2; ++s) {
      const unsigned short* Ap = As + (s ? a_e1 : a_e0);
      const unsigned short* Bp = Bs + (s ? b_e1 : b_e0);
      bf16x8 af[4], bf[4];
#pragma unroll
      for (int mi = 0; mi < 4; ++mi) af[mi] = *(const bf16x8*)(Ap + mi * 1024);
#pragma unroll
      for (int ni = 0; ni < 4; ++ni) bf[ni] = *(const bf16x8*)(Bp + ni * 1024);
#pragma unroll
      for (int mi = 0; mi < 4; ++mi)
#pragma unroll
        for (int ni = 0; ni < 4; ++ni)
          acc[mi][ni] = __builtin_amdgcn_mfma_f32_16x16x32_bf16(af[mi], bf[ni], acc[mi][ni], 0, 0, 0);
    }
  }

  const int rq = fq * 4;
#pragma unroll
  for (int mi = 0; mi < 4; ++mi) {
#pragma unroll
    for (int r = 0; r < 4; ++r) {
      int row = m0 + wm + mi * 16 + rq + r;
      if (row < count) {
        int t = perm[base + row];
        float* o = out + (size_t)t * DM + n0 + wn;
#pragma unroll
        for (int ni = 0; ni < 4; ++ni)
          o[ni * 16 + fm] = acc[mi][ni][r];
      }
    }
  }
}

// ---------------- launch ----------------

extern "C" void kernel_launch(void* const* d_in, const int* in_sizes, int n_in,
                              void* d_out, int out_size, void* d_ws, size_t ws_size,
                              hipStream_t stream) {
  const float* x  = (const float*)d_in[0];
  const float* gw = (const float*)d_in[1];
  const float* uw = (const float*)d_in[2];
  const float* dw = (const float*)d_in[3];
  const int* tsi  = (const int*)d_in[4];
  float* out = (float*)d_out;

  char* ws = (char*)d_ws;
  int* meta  = (int*)ws;                         // 64 ints
  int* part  = (int*)(ws + 256);                 // 32*9 ints
  int2* table = (int2*)(ws + 2048);              // 132 entries
  int* rank  = (int*)(ws + 4096);                // NT ints
  int* perm  = (int*)(ws + 4096 + NT * 4);       // NT ints
  unsigned short* xc  = (unsigned short*)(ws + (1 << 18));  // 32 MiB compacted
  unsigned short* gwt = xc + (size_t)NT * DM;               // 8 MiB
  unsigned short* uwt = gwt + (size_t)NSEG * HS * DM;       // 8 MiB
  unsigned short* dwt = uwt + (size_t)NSEG * HS * DM;       // 8 MiB
  unsigned short* hid = dwt + (size_t)NSEG * DM * HS;       // 32 MiB compacted

  k_scan<<<32, 256, 0, stream>>>(tsi, part);
  k_base<<<1, 64, 0, stream>>>(part, meta, table);
  k_rank<<<NT / 256, 256, 0, stream>>>(tsi, meta, rank, perm);
  k_prep<<<8192 + 2048, 256, 0, stream>>>((const float4*)x, rank, (uint4*)xc, gw, uw, gwt, uwt);
  k_gateup<<<1024 + 16 * 132, 256, 0, stream>>>(xc, gwt, uwt, meta, table, dw, dwt, hid);
  k_down<<<8 * 132, 256, 0, stream>>>(hid, dwt, meta, table, perm, out);
}

// Round 5
// 321.181 us; speedup vs baseline: 1.2731x; 1.0406x over previous
//
#include <hip/hip_runtime.h>
#include <hip/hip_bf16.h>
#include <math.h>

#define NT   16384
#define DM   1024
#define NSEG 4
#define BK   64
#define HS   1024

typedef __attribute__((ext_vector_type(8))) short bf16x8;
typedef __attribute__((ext_vector_type(4))) float f32x4;

typedef __attribute__((address_space(1))) unsigned int gu32;
typedef __attribute__((address_space(3))) unsigned int lu32;

__device__ __forceinline__ void gll16(const void* g, void* l) {
  __builtin_amdgcn_global_load_lds((gu32*)(unsigned long long)g,
                                   (lu32*)(unsigned int)(unsigned long long)l,
                                   16, 0, 0);
}

__device__ __forceinline__ unsigned short cvt_bf16(float f) {
  unsigned int u = __float_as_uint(f);
  u += 0x7fffu + ((u >> 16) & 1u);   // RNE
  return (unsigned short)(u >> 16);
}

// part[b][0..3] = seg counts of tokens [256b, 256b+256) under the DECIDED
//                 interpretation; part[b][4] = 1 if indices are int32.
// Detection is strictly in-bounds: only words [0, 16384) are read before the
// decision (valid for both dtypes); the upper half is read only if int64.

// K1: blocks [0,64) = scan; blocks [64, 64+3072) = weight transposes.
__global__ __launch_bounds__(256) void k_prepw(
    const int* __restrict__ idx, int* __restrict__ part,
    const float* __restrict__ gw, const float* __restrict__ uw, const float* __restrict__ dw,
    unsigned short* __restrict__ gwt, unsigned short* __restrict__ uwt,
    unsigned short* __restrict__ dwt) {
  __shared__ float tile[64][65];
  const int bid = blockIdx.x, tid = threadIdx.x;
  if (bid < 64) {
    __shared__ int sc[5];
    if (tid < 5) sc[tid] = 0;
    __syncthreads();
    int lane = tid & 63;
    int w32 = idx[bid * 256 + tid];               // in bounds for both dtypes
    unsigned long long m = __ballot((tid & 1) && (w32 != 0));
    if (lane == 0 && m) atomicAdd(&sc[4], 1);     // odd word nonzero => int32
    __syncthreads();
    int is32 = (sc[4] != 0);
    int s = w32;
    if (!is32) s = idx[bid * 512 + 2 * tid];      // only if genuinely int64
#pragma unroll
    for (int q = 0; q < 4; ++q) {
      m = __ballot(s == q);
      if (lane == 0 && m) atomicAdd(&sc[q], (int)__popcll(m));
    }
    __syncthreads();
    if (tid < 4) part[bid * 8 + tid] = sc[tid];
    if (tid == 4) part[bid * 8 + 4] = is32;
    return;
  }
  int tb = bid - 64;                              // 0..3071
  int mtx = tb >> 10, seg = (tb >> 8) & 3, tl = tb & 255;
  const float* src = (mtx == 0 ? gw : mtx == 1 ? uw : dw) + (size_t)seg * DM * HS;
  unsigned short* dst = (mtx == 0 ? gwt : mtx == 1 ? uwt : dwt) + (size_t)seg * DM * HS;
  int n0 = (tl & 15) * 64, k0 = (tl >> 4) * 64;
  int col = tid & 63, rb = tid >> 6;
#pragma unroll
  for (int i = 0; i < 64; i += 4)
    tile[i + rb][col] = src[(size_t)(k0 + i + rb) * 1024 + n0 + col];
  __syncthreads();
  int kp = tid & 31, nb = tid >> 5;
#pragma unroll
  for (int j = 0; j < 64; j += 8) {
    int nn = j + nb;
    unsigned int w = (unsigned)cvt_bf16(tile[2 * kp][nn]) |
                     ((unsigned)cvt_bf16(tile[2 * kp + 1][nn]) << 16);
    *(unsigned int*)(dst + (size_t)(n0 + nn) * 1024 + k0 + 2 * kp) = w;
  }
}

// K2: deterministic rank (no global atomics) + x f32->bf16 compaction.
// 2048 blocks; block handles 8 tokens [8*bid, 8*bid+8) inside chunk bid>>5.
__global__ __launch_bounds__(256) void k_cvtrank(
    const int* __restrict__ idx, const int* __restrict__ part,
    const float4* __restrict__ x,
    int* __restrict__ meta, int2* __restrict__ table,
    int* __restrict__ perm, uint4* __restrict__ xc) {
  __shared__ int cnt[64][4];
  __shared__ int wsum[4][4];
  __shared__ int tot[4], pref[4], gbase[4];
  __shared__ int rnk8[8];
  __shared__ int flag_s;
  const int tid = threadIdx.x, bid = blockIdx.x;
  const int lane = tid & 63, wv = tid >> 6;
  const int c = bid >> 5;                 // chunk 0..63
  const int p0 = (bid & 31) * 8;          // target window within chunk

  if (tid == 0) flag_s = part[c * 8 + 4];
  if (wv == 0) {
#pragma unroll
    for (int s = 0; s < 4; ++s) cnt[lane][s] = part[lane * 8 + s];
  }
  __syncthreads();
  const int is32 = flag_s;
  int tok = c * 256 + tid;
  int s_t = is32 ? idx[tok] : idx[2 * tok];
  int myr = 0;
  unsigned long long lt = (1ull << lane) - 1;
#pragma unroll
  for (int q = 0; q < 4; ++q) {
    unsigned long long m = __ballot(s_t == q);
    if (lane == 0) wsum[wv][q] = (int)__popcll(m);
    if (s_t == q) myr = (int)__popcll(m & lt);
  }
  __syncthreads();
  if (tid < 4) {
    int s = tid, t = 0, p = 0;
    for (int b = 0; b < 64; ++b) { if (b == c) p = t; t += cnt[b][s]; }
    tot[s] = t; pref[s] = p;
  }
  __syncthreads();
  if (tid == 0) {
    gbase[0] = 0;
    for (int s = 1; s < 4; ++s) gbase[s] = gbase[s - 1] + tot[s - 1];
    if (bid == 0) {
      int nt = 0;
      for (int s = 0; s < 4; ++s) {
        meta[s] = tot[s]; meta[5 + s] = gbase[s];
        for (int m0 = 0; m0 < tot[s]; m0 += 128) table[nt++] = make_int2(s, m0);
      }
      for (; nt < 132; ++nt) table[nt] = make_int2(-1, 0);
    }
  }
  __syncthreads();
  int wpre = 0;
  for (int w2 = 0; w2 < wv; ++w2) wpre += wsum[w2][s_t];
  int r = gbase[s_t] + pref[s_t] + wpre + myr;
  if (tid >= p0 && tid < p0 + 8) {
    perm[r] = tok;
    rnk8[tid - p0] = r;
  }
  __syncthreads();
  // convert 8 tokens: 32 lanes per token, 1024 f32 each
  const int j = tid >> 5, l2 = tid & 31;
  const int tok8 = bid * 8 + j;
  const float4* src = x + (size_t)tok8 * 256;
  uint4* dst = xc + (size_t)rnk8[j] * 128;
#pragma unroll
  for (int it = 0; it < 4; ++it) {
    float4 a = src[it * 64 + l2 * 2];
    float4 b = src[it * 64 + l2 * 2 + 1];
    uint4 o;
    o.x = cvt_bf16(a.x) | ((unsigned)cvt_bf16(a.y) << 16);
    o.y = cvt_bf16(a.z) | ((unsigned)cvt_bf16(a.w) << 16);
    o.z = cvt_bf16(b.x) | ((unsigned)cvt_bf16(b.y) << 16);
    o.w = cvt_bf16(b.z) | ((unsigned)cvt_bf16(b.w) << 16);
    dst[it * 32 + l2] = o;
  }
}

// ---------------- GEMM 1: gate+up fused, silu epilogue ----------------
__global__ __launch_bounds__(256) void k_gateup(
    const unsigned short* __restrict__ xc,
    const unsigned short* __restrict__ gwt,
    const unsigned short* __restrict__ uwt,
    const int* __restrict__ meta,
    const int2* __restrict__ table,
    unsigned short* __restrict__ hidden) {
  __shared__ __align__(16) unsigned short As[128 * BK];
  __shared__ __align__(16) unsigned short Bg[64 * BK];
  __shared__ __align__(16) unsigned short Bu[64 * BK];
  const int bid = blockIdx.x, tid = threadIdx.x;
  const int2 te = table[bid >> 4];
  if (te.x < 0) return;
  const int seg = te.x, m0 = te.y;
  const int count = meta[seg], base = meta[5 + seg];
  const int n0 = (bid & 15) * 64;

  const int lane = tid & 63;
  const int wave = tid >> 6;

  const unsigned short* ap[4];
#pragma unroll
  for (int is = 0; is < 4; ++is) {
    int c = is * 256 + tid;
    int m = c >> 3;
    int kb = (c & 7) ^ (m & 7);
    int row = m0 + m;
    row = row < count ? row : count - 1;
    ap[is] = xc + (size_t)(base + row) * DM + kb * 8;
  }
  const unsigned short *gp[2], *up[2];
#pragma unroll
  for (int is = 0; is < 2; ++is) {
    int c = is * 256 + tid;
    int n = c >> 3;
    int kb = (c & 7) ^ (n & 7);
    gp[is] = gwt + (size_t)(seg * HS + n0 + n) * DM + kb * 8;
    up[is] = uwt + (size_t)(seg * HS + n0 + n) * DM + kb * 8;
  }

  f32x4 accg[4][2] = {};
  f32x4 accu[4][2] = {};
  const int wm = (wave & 1) * 64;
  const int wn = (wave >> 1) * 32;
  const int fm = lane & 15;
  const int fq = lane >> 4;
  const int fx = lane & 7;
  const int a_e0 = (wm + fm) * 64 + ((fq) ^ fx) * 8;
  const int a_e1 = (wm + fm) * 64 + ((4 + fq) ^ fx) * 8;
  const int b_e0 = (wn + fm) * 64 + ((fq) ^ fx) * 8;
  const int b_e1 = (wn + fm) * 64 + ((4 + fq) ^ fx) * 8;

  for (int kt = 0; kt < DM / BK; ++kt) {
    __syncthreads();
#pragma unroll
    for (int is = 0; is < 4; ++is)
      gll16(ap[is], (char*)As + (is * 256 + wave * 64) * 16);
#pragma unroll
    for (int is = 0; is < 2; ++is) {
      gll16(gp[is], (char*)Bg + (is * 256 + wave * 64) * 16);
      gll16(up[is], (char*)Bu + (is * 256 + wave * 64) * 16);
    }
#pragma unroll
    for (int is = 0; is < 4; ++is) ap[is] += BK;
#pragma unroll
    for (int is = 0; is < 2; ++is) { gp[is] += BK; up[is] += BK; }
    __syncthreads();
#pragma unroll
    for (int s = 0; s < 2; ++s) {
      const unsigned short* Ap = As + (s ? a_e1 : a_e0);
      const unsigned short* Gp = Bg + (s ? b_e1 : b_e0);
      const unsigned short* Up = Bu + (s ? b_e1 : b_e0);
      bf16x8 af[4], bg2[2], bu2[2];
#pragma unroll
      for (int mi = 0; mi < 4; ++mi) af[mi] = *(const bf16x8*)(Ap + mi * 1024);
#pragma unroll
      for (int ni = 0; ni < 2; ++ni) {
        bg2[ni] = *(const bf16x8*)(Gp + ni * 1024);
        bu2[ni] = *(const bf16x8*)(Up + ni * 1024);
      }
#pragma unroll
      for (int mi = 0; mi < 4; ++mi)
#pragma unroll
        for (int ni = 0; ni < 2; ++ni) {
          accg[mi][ni] = __builtin_amdgcn_mfma_f32_16x16x32_bf16(af[mi], bg2[ni], accg[mi][ni], 0, 0, 0);
          accu[mi][ni] = __builtin_amdgcn_mfma_f32_16x16x32_bf16(af[mi], bu2[ni], accu[mi][ni], 0, 0, 0);
        }
    }
  }

  const int rq = fq * 4;
#pragma unroll
  for (int mi = 0; mi < 4; ++mi) {
#pragma unroll
    for (int r = 0; r < 4; ++r) {
      int row = m0 + wm + mi * 16 + rq + r;
      if (row < count) {
        unsigned short* h = hidden + (size_t)(base + row) * HS + n0 + wn;
#pragma unroll
        for (int ni = 0; ni < 2; ++ni) {
          float gv = accg[mi][ni][r];
          float uv = accu[mi][ni][r];
          float sig = 1.0f / (1.0f + __expf(-gv));
          h[ni * 16 + fm] = cvt_bf16(gv * sig * uv);
        }
      }
    }
  }
}

// ---------------- GEMM 2: down, scatter rows to out ----------------
__global__ __launch_bounds__(256) void k_down(
    const unsigned short* __restrict__ hidden,
    const unsigned short* __restrict__ dwt,
    const int* __restrict__ meta,
    const int2* __restrict__ table,
    const int* __restrict__ perm,
    float* __restrict__ out) {
  __shared__ __align__(16) unsigned short As[128 * BK];
  __shared__ __align__(16) unsigned short Bs[128 * BK];
  const int bid = blockIdx.x, tid = threadIdx.x;
  const int2 te = table[bid >> 3];
  if (te.x < 0) return;
  const int seg = te.x, m0 = te.y;
  const int count = meta[seg], base = meta[5 + seg];
  const int n0 = (bid & 7) * 128;

  const int lane = tid & 63;
  const int wave = tid >> 6;

  const unsigned short *ap[4], *bp[4];
#pragma unroll
  for (int is = 0; is < 4; ++is) {
    int c = is * 256 + tid;
    int m = c >> 3;
    int kb = (c & 7) ^ (m & 7);
    int row = m0 + m;
    row = row < count ? row : count - 1;
    ap[is] = hidden + (size_t)(base + row) * HS + kb * 8;
    bp[is] = dwt + (size_t)(seg * DM + n0 + m) * HS + kb * 8;
  }

  f32x4 acc[4][4] = {};
  const int wm = (wave & 1) * 64;
  const int wn = (wave >> 1) * 64;
  const int fm = lane & 15;
  const int fq = lane >> 4;
  const int fx = lane & 7;
  const int a_e0 = (wm + fm) * 64 + ((fq) ^ fx) * 8;
  const int a_e1 = (wm + fm) * 64 + ((4 + fq) ^ fx) * 8;
  const int b_e0 = (wn + fm) * 64 + ((fq) ^ fx) * 8;
  const int b_e1 = (wn + fm) * 64 + ((4 + fq) ^ fx) * 8;

  for (int kt = 0; kt < HS / BK; ++kt) {
    __syncthreads();
#pragma unroll
    for (int is = 0; is < 4; ++is) {
      gll16(ap[is], (char*)As + (is * 256 + wave * 64) * 16);
      gll16(bp[is], (char*)Bs + (is * 256 + wave * 64) * 16);
    }
#pragma unroll
    for (int is = 0; is < 4; ++is) { ap[is] += BK; bp[is] += BK; }
    __syncthreads();
#pragma unroll
    for (int s = 0; s < 2; ++s) {
      const unsigned short* Ap = As + (s ? a_e1 : a_e0);
      const unsigned short* Bp = Bs + (s ? b_e1 : b_e0);
      bf16x8 af[4], bf[4];
#pragma unroll
      for (int mi = 0; mi < 4; ++mi) af[mi] = *(const bf16x8*)(Ap + mi * 1024);
#pragma unroll
      for (int ni = 0; ni < 4; ++ni) bf[ni] = *(const bf16x8*)(Bp + ni * 1024);
#pragma unroll
      for (int mi = 0; mi < 4; ++mi)
#pragma unroll
        for (int ni = 0; ni < 4; ++ni)
          acc[mi][ni] = __builtin_amdgcn_mfma_f32_16x16x32_bf16(af[mi], bf[ni], acc[mi][ni], 0, 0, 0);
    }
  }

  const int rq = fq * 4;
#pragma unroll
  for (int mi = 0; mi < 4; ++mi) {
#pragma unroll
    for (int r = 0; r < 4; ++r) {
      int row = m0 + wm + mi * 16 + rq + r;
      if (row < count) {
        int t = perm[base + row];
        float* o = out + (size_t)t * DM + n0 + wn;
#pragma unroll
        for (int ni = 0; ni < 4; ++ni)
          o[ni * 16 + fm] = acc[mi][ni][r];
      }
    }
  }
}

// ---------------- launch ----------------

extern "C" void kernel_launch(void* const* d_in, const int* in_sizes, int n_in,
                              void* d_out, int out_size, void* d_ws, size_t ws_size,
                              hipStream_t stream) {
  const float* x  = (const float*)d_in[0];
  const float* gw = (const float*)d_in[1];
  const float* uw = (const float*)d_in[2];
  const float* dw = (const float*)d_in[3];
  const int* tsi  = (const int*)d_in[4];
  float* out = (float*)d_out;

  char* ws = (char*)d_ws;
  int*  meta  = (int*)ws;                        // 64 ints
  int*  part  = (int*)(ws + 256);                // 64*8 ints
  int2* table = (int2*)(ws + 4096);              // 132 entries
  int*  perm  = (int*)(ws + 8192);               // NT ints (64 KiB)
  unsigned short* xc  = (unsigned short*)(ws + (1 << 18));  // 32 MiB compacted
  unsigned short* gwt = xc + (size_t)NT * DM;               // 8 MiB
  unsigned short* uwt = gwt + (size_t)NSEG * HS * DM;       // 8 MiB
  unsigned short* dwt = uwt + (size_t)NSEG * HS * DM;       // 8 MiB
  unsigned short* hid = dwt + (size_t)NSEG * DM * HS;       // 32 MiB compacted

  k_prepw<<<64 + 3072, 256, 0, stream>>>(tsi, part, gw, uw, dw, gwt, uwt, dwt);
  k_cvtrank<<<2048, 256, 0, stream>>>(tsi, part, (const float4*)x, meta, table, perm, (uint4*)xc);
  k_gateup<<<16 * 132, 256, 0, stream>>>(xc, gwt, uwt, meta, table, hid);
  k_down<<<8 * 132, 256, 0, stream>>>(hid, dwt, meta, table, perm, out);
}